// Round 2
// baseline (171.929 us; speedup 1.0000x reference)
//
#include <hip/hip_runtime.h>
#include <hip/hip_bf16.h>
#include <math.h>

// Masked dot-product attention, bf16 MFMA flash kernel, round 5.
// B=32, LQ=LK=2048, D=64. S^T = K*Q^T and O^T = V^T*P^T with 32x32x16 MFMA.
// Round 4 structure (2-way KV split across wave pairs, defer-max) + fix:
//  - __syncthreads() after the main loop, BEFORE the merge writes. The merge
//    reuses group 1's LDS buffers; without the barrier, wave 2 could overwrite
//    Kl[1]/Vt[1] while wave 3 was still reading them for its final MFMAs
//    (the round-4 NaN).

#define B_    32
#define LQ_   2048
#define LK_   2048
#define D_    64

typedef __attribute__((ext_vector_type(8)))  short bf16x8;
typedef __attribute__((ext_vector_type(4)))  float f32x4;
typedef __attribute__((ext_vector_type(16))) float f32x16;

static __device__ __forceinline__ unsigned pk_bf16(float a, float b) {
    __hip_bfloat162 h = __float22bfloat162_rn(float2{a, b});
    return *(unsigned*)&h;   // x in low 16 bits, y in high
}

__global__ __launch_bounds__(256, 2) void fa_mfma5_kernel(
    const float* __restrict__ Q, const float* __restrict__ K,
    const float* __restrict__ V, const int* __restrict__ vlen,
    float* __restrict__ O)
{
    // Per-group K tile [key][dim] and V^T tile [dim][key], bf16 64x64, double
    // buffered. 16B chunks swizzled: pos = chunk ^ (row & 7).
    __shared__ __align__(16) short Kl[2][2][64 * 64];
    __shared__ __align__(16) short Vt[2][2][64 * 64];

    const int tid  = threadIdx.x;          // 0..255
    const int wid  = tid >> 6;             // 0..3
    const int grp  = wid >> 1;             // KV-split group: handles tiles t%2==grp
    const int wsub = wid & 1;              // 32-row q sub-block within the 64 rows
    const int lane = tid & 63;
    const int c31  = lane & 31;
    const int h    = lane >> 5;
    const int ltid = tid & 127;            // staging id within group

    const int b  = blockIdx.y;
    const int q0 = blockIdx.x * 64 + wsub * 32;
    const int vl = vlen[b];
    const int nt = (vl + 63) >> 6;         // tiles of 64 keys
    const int ni = (nt + 1) >> 1;          // iterations per group (lockstep)

    const float qscale = 0.125f * 1.44269504088896340736f;  // 1/sqrt(64)*log2(e)

    // ---- Q B-frags in registers: B[k=dim][n=q], dim = ks*16 + h*8 + j ----
    unsigned qfrag[4][4];
#pragma unroll
    for (int ks = 0; ks < 4; ++ks) {
        const float* qp = Q + ((size_t)(b * LQ_ + q0 + c31)) * D_ + ks * 16 + h * 8;
        f32x4 t0 = *(const f32x4*)qp;
        f32x4 t1 = *(const f32x4*)(qp + 4);
#pragma unroll
        for (int jj = 0; jj < 2; ++jj) {
            qfrag[ks][jj]     = pk_bf16(t0[2*jj] * qscale, t0[2*jj+1] * qscale);
            qfrag[ks][jj + 2] = pk_bf16(t1[2*jj] * qscale, t1[2*jj+1] * qscale);
        }
    }

    f32x16 oacc[2];     // O^T acc: dim row = dt*32 + (r&3)+8*(r>>2)+4h, col q = c31
#pragma unroll
    for (int dt = 0; dt < 2; ++dt)
#pragma unroll
        for (int r = 0; r < 16; ++r) oacc[dt][r] = 0.f;
    float mrun = -INFINITY, lrun = 0.f;

    // staging maps (within group)
    const int skey = ltid >> 1, skh = ltid & 1;        // K: half-row each
    const int vkg = ltid >> 4, vdg = ltid & 15;        // V: 8 keys x 4 dims

    const float* kgp = K + ((size_t)(b * LK_ + skey)) * D_ + skh * 32;
    const float* vgp = V + ((size_t)(b * LK_ + vkg * 8)) * D_ + vdg * 4;

    f32x4 kr[8], vr[8];
    // ---- prologue: prefetch this group's tile (tile index == grp) ----
    {
        const size_t off = (size_t)(grp * 64) * D_;    // always in-bounds (LK=2048)
#pragma unroll
        for (int i = 0; i < 8; ++i) kr[i] = *(const f32x4*)(kgp + off + 4 * i);
#pragma unroll
        for (int i = 0; i < 8; ++i) vr[i] = *(const f32x4*)(vgp + off + (size_t)i * D_);
    }

    for (int it = 0; it < ni; ++it) {
        const int t   = 2 * it + grp;
        const int k0  = t * 64;
        const int buf = it & 1;
        const bool active = (t < nt);      // only group 1's last iter can be idle

        // ---- cvt + write tile t to this group's LDS ----
        if (active) {
            unsigned pk32[16];
#pragma unroll
            for (int m = 0; m < 16; ++m)
                pk32[m] = pk_bf16(kr[m >> 1][2 * (m & 1)], kr[m >> 1][2 * (m & 1) + 1]);
#pragma unroll
            for (int cch = 0; cch < 4; ++cch) {
                const int pos = (skh * 4 + cch) ^ (skey & 7);
                *(bf16x8*)&Kl[grp][buf][skey * 64 + pos * 8] = *(bf16x8*)&pk32[4 * cch];
            }
#pragma unroll
            for (int dr = 0; dr < 4; ++dr) {
                unsigned w[4];
#pragma unroll
                for (int p = 0; p < 4; ++p)
                    w[p] = pk_bf16(vr[2 * p][dr], vr[2 * p + 1][dr]);
                const int dim = vdg * 4 + dr;
                const int pos = vkg ^ (dim & 7);
                *(bf16x8*)&Vt[grp][buf][dim * 64 + pos * 8] = *(bf16x8*)&w[0];
            }
        }
        // ---- issue prefetch for tile t+2 (in flight across the barrier) ----
        if (t + 2 < nt) {
            const float* kn = kgp + (size_t)(k0 + 128) * D_;
            const float* vn = vgp + (size_t)(k0 + 128) * D_;
#pragma unroll
            for (int i = 0; i < 8; ++i) kr[i] = *(const f32x4*)(kn + 4 * i);
#pragma unroll
            for (int i = 0; i < 8; ++i) vr[i] = *(const f32x4*)(vn + (size_t)i * D_);
        }
        __syncthreads();
        if (!active) continue;

        // ---- S^T = K * Q^T : 2 key-tiles x 4 k-steps of 32x32x16 ----
        f32x16 st[2];
#pragma unroll
        for (int s = 0; s < 2; ++s) {
#pragma unroll
            for (int r = 0; r < 16; ++r) st[s][r] = 0.f;
#pragma unroll
            for (int ks = 0; ks < 4; ++ks) {
                const int pos = (ks * 2 + h) ^ (c31 & 7);
                bf16x8 kf = *(const bf16x8*)&Kl[grp][buf][(s * 32 + c31) * 64 + pos * 8];
                st[s] = __builtin_amdgcn_mfma_f32_32x32x16_bf16(
                    kf, *(const bf16x8*)&qfrag[ks][0], st[s], 0, 0, 0);
            }
        }

        // ---- mask tail keys >= vl (only the true last tile) ----
        if (k0 + 64 > vl) {
#pragma unroll
            for (int s = 0; s < 2; ++s) {
                const int base = k0 + s * 32 + 4 * h;
#pragma unroll
                for (int r = 0; r < 16; ++r) {
                    const int key = base + (r & 3) + 8 * (r >> 2);
                    if (key >= vl) st[s][r] = -1e30f;
                }
            }
        }

        // ---- online softmax (log2 domain), q column = c31, defer-max ----
        float tm = st[0][0];
#pragma unroll
        for (int s = 0; s < 2; ++s)
#pragma unroll
            for (int r = 0; r < 16; ++r) tm = fmaxf(tm, st[s][r]);
        tm = fmaxf(tm, __shfl_xor(tm, 32));
        if (__any(tm > mrun + 8.f)) {          // rare after the first tile
            const float mnew = fmaxf(mrun, tm);
            const float corr = exp2f(mrun - mnew);
            lrun *= corr;
#pragma unroll
            for (int dt = 0; dt < 2; ++dt)
#pragma unroll
                for (int r = 0; r < 16; ++r) oacc[dt][r] *= corr;
            mrun = mnew;
        }
        float rs = 0.f;
#pragma unroll
        for (int s = 0; s < 2; ++s)
#pragma unroll
            for (int r = 0; r < 16; ++r) {
                const float p = exp2f(st[s][r] - mrun);   // bounded by 2^8
                st[s][r] = p;
                rs += p;
            }
        rs += __shfl_xor(rs, 32);
        lrun += rs;

        // ---- pack P to bf16 pairs: pk[s][m] = keys (8*(m>>1)+2*(m&1)+4h, +1) ----
        unsigned pk[2][8];
#pragma unroll
        for (int s = 0; s < 2; ++s)
#pragma unroll
            for (int m = 0; m < 8; ++m)
                pk[s][m] = pk_bf16(st[s][2 * m], st[s][2 * m + 1]);

        // ---- O^T += V^T * P^T : 4 k-steps x 2 dim-tiles ----
#pragma unroll
        for (int kq = 0; kq < 4; ++kq) {
            const int s = kq >> 1, A4 = (kq & 1) * 4;
            unsigned p0 = pk[s][A4], p1 = pk[s][A4+1], p2 = pk[s][A4+2], p3 = pk[s][A4+3];
            unsigned xp0 = __shfl_xor((int)p0, 32);
            unsigned xp1 = __shfl_xor((int)p1, 32);
            unsigned xp2 = __shfl_xor((int)p2, 32);
            unsigned xp3 = __shfl_xor((int)p3, 32);
            unsigned pf[4];
            pf[0] = h ? xp2 : p0;
            pf[1] = h ? xp3 : p1;
            pf[2] = h ? p2  : xp0;
            pf[3] = h ? p3  : xp1;
            const bf16x8 pfr = *(const bf16x8*)&pf[0];
#pragma unroll
            for (int dt = 0; dt < 2; ++dt) {
                const int pos = (kq * 2 + h) ^ (c31 & 7);
                bf16x8 vf = *(const bf16x8*)&Vt[grp][buf][(dt * 32 + c31) * 64 + pos * 8];
                oacc[dt] = __builtin_amdgcn_mfma_f32_32x32x16_bf16(vf, pfr, oacc[dt], 0, 0, 0);
            }
        }
    }

    // ---- ensure ALL waves are done reading Kl[1]/Vt[1] before the merge
    //      scratch overwrites them (this barrier was the round-4 NaN fix) ----
    __syncthreads();

    // ---- merge the two KV-split partials via LDS (reuse group-1 buffers) ----
    float* xO = (float*)&Kl[1][0][0];   // [wsub][dim 0..63][q 0..31] = 4096 floats
    float* xM = (float*)&Vt[1][0][0];   // m at [wsub*64 + q], l at [wsub*64+32+q]
    if (grp == 1) {
#pragma unroll
        for (int dt = 0; dt < 2; ++dt)
#pragma unroll
            for (int r = 0; r < 16; ++r) {
                const int dim = dt * 32 + (r & 3) + 8 * (r >> 2) + 4 * h;
                xO[wsub * 2048 + dim * 32 + c31] = oacc[dt][r];
            }
        if (h == 0) {
            xM[wsub * 64 + c31]      = mrun;   // -inf if this group had no tiles
            xM[wsub * 64 + 32 + c31] = lrun;
        }
    }
    __syncthreads();
    if (grp == 0) {
        const float m1 = xM[wsub * 64 + c31];
        const float l1 = xM[wsub * 64 + 32 + c31];
        const float mf = fmaxf(mrun, m1);        // mrun always finite (tile 0)
        const float c0 = exp2f(mrun - mf);
        const float c1 = exp2f(m1 - mf);         // 0 if m1 == -inf
        const float inv = 1.f / (lrun * c0 + l1 * c1);
        float* op = O + ((size_t)(b * LQ_ + q0 + c31)) * D_;
#pragma unroll
        for (int dt = 0; dt < 2; ++dt)
#pragma unroll
            for (int g = 0; g < 4; ++g) {
                f32x4 v;
#pragma unroll
                for (int j = 0; j < 4; ++j) {
                    const int dim = dt * 32 + 8 * g + 4 * h + j;
                    v[j] = (oacc[dt][4 * g + j] * c0 +
                            xO[wsub * 2048 + dim * 32 + c31] * c1) * inv;
                }
                *(f32x4*)(op + dt * 32 + 8 * g + 4 * h) = v;
            }
    }
}

extern "C" void kernel_launch(void* const* d_in, const int* in_sizes, int n_in,
                              void* d_out, int out_size, void* d_ws, size_t ws_size,
                              hipStream_t stream) {
    const float* Q    = (const float*)d_in[0];
    const float* K    = (const float*)d_in[1];
    const float* V    = (const float*)d_in[2];
    const int*   vlen = (const int*)d_in[3];
    float*       O    = (float*)d_out;

    dim3 grid(LQ_ / 64, B_);
    dim3 block(256);
    fa_mfma5_kernel<<<grid, block, 0, stream>>>(Q, K, V, vlen, O);
}